// Round 12
// baseline (250.760 us; speedup 1.0000x reference)
//
#include <hip/hip_runtime.h>
#include <hip/hip_bf16.h>

// IntraCellularAttention: B=1024, D_INNER=4096, D_STATE=16, D_ATTN=16
// out[b,d,s] = h[b,d,s] + gate * sum_t attn[b,s,t] * h[b,d,t]
// attn[s,t] = softmax_t( (Q K^T)[s,t] * 0.25 ),  Q[s,a] = sum_d h[b,d,s] Wq[a,d]
//
// Register-resident h: 512 threads (8 waves), 1 block/batch, grid 1024.
// Each lane holds 32 float4 of h loaded ONCE, fully coalesced, 3-chunk
// lookahead. launch_bounds(512,1).
//   Phase 1: per 32-row chunk: regs -> LDS tile -> col-read A-frag,
//            mfma_16x16x32_bf16 vs W row slices (L2).
//   Phase 2: softmax on 256 threads, fold gate into Ms.
//   Phase 3 (round-11 change): OPERAND-SWAPPED PV -- D' = Ms * H^T:
//            A-frag = Ms (hoisted), B-frag = h tile col-read from LDS.
//            D' lands in store layout (lane (sa,kb) = out[d+sa][kb*4..+3]):
//            no transpose round-trip, 2 wave_barriers/tile instead of 4.
//            Residual from the same LDS tile. Coalesced NT f4 stores.

constexpr int DI = 4096;
constexpr int DS = 16;
constexpr int NW = 8;                       // waves per block

typedef __attribute__((ext_vector_type(8))) short bf16x8;
typedef __attribute__((ext_vector_type(4))) float f32x4;

static __device__ __forceinline__ short f2bf(float x) {
    union { __hip_bfloat16 h; short s; } u;
    u.h = __float2bfloat16(x);
    return u.s;
}

__global__ __launch_bounds__(512, 1) void ica_fused(
    const float* __restrict__ h,
    const float* __restrict__ Wq,
    const float* __restrict__ Wk,
    const float* __restrict__ gate,
    float* __restrict__ out)
{
    const int b    = blockIdx.x;
    const int tid  = threadIdx.x;
    const int lane = tid & 63;
    const int wv   = tid >> 6;              // 0..7

    const float* __restrict__ hbase = h   + (size_t)b * (DI * DS);
    float*       __restrict__ obase = out + (size_t)b * (DI * DS);

    __shared__ float st[NW][32][20];        // per-wave transpose tile
    __shared__ float qp[NW][16][20];        // Q partials [w][s][a]
    __shared__ float kp[NW][16][20];        // K partials
    __shared__ float Qs[16][20];
    __shared__ float Ks[16][20];
    __shared__ float Ms[16][20];            // Ms[s][t] = g * attn[s][t]

    const int sa   = lane & 15;             // A/B row index and MFMA col
    const int kb   = lane >> 4;             // k-subblock 0..3
    const int row  = lane >> 2;             // coalesced-layout row (0..15)
    const int quad = lane & 3;              // float4 slot within row

    // wave's 512 rows as 2048 float4; lane's j-th f4 = row j*16+row, quad
    const float4* __restrict__ h4 = (const float4*)hbase + (size_t)wv * 2048;
    const int d0w = wv * 512;

    float4 H[32];                           // register-resident h slice

    // ---------------- Phase 1: Q,K via MFMA, regs->LDS transpose ----------
    {
        const float* __restrict__ wqb = Wq + (size_t)sa * DI;
        const float* __restrict__ wkb = Wk + (size_t)sa * DI;

        f32x4 accQ = {0.f, 0.f, 0.f, 0.f};
        f32x4 accK = {0.f, 0.f, 0.f, 0.f};

        float4 WQ0[3], WQ1[3], WK0[3], WK1[3];   // 3-slot W landing (L2)

#define LD_CHUNK(C, SL) do {                                                \
        H[2*(C)]   = h4[(2*(C)) * 64 + lane];                               \
        H[2*(C)+1] = h4[(2*(C)+1) * 64 + lane];                             \
        const int db_ = d0w + (C) * 32 + kb * 8;                            \
        WQ0[SL] = *(const float4*)(wqb + db_);                              \
        WQ1[SL] = *(const float4*)(wqb + db_ + 4);                          \
        WK0[SL] = *(const float4*)(wkb + db_);                              \
        WK1[SL] = *(const float4*)(wkb + db_ + 4);                          \
    } while (0)

        LD_CHUNK(0, 0);
        LD_CHUNK(1, 1);
        LD_CHUNK(2, 2);

        #pragma unroll
        for (int c = 0; c < 16; ++c) {
            const int sl = c % 3;
            // stage chunk c (32 rows) into the wave tile
            *(float4*)&st[wv][row][quad * 4]      = H[2*c];
            *(float4*)&st[wv][row + 16][quad * 4] = H[2*c + 1];

            // consume this slot's W into bf16 regs BEFORE the lookahead
            // overwrites it (lookahead distance == slot count)
            bf16x8 bq, bk;
            bq[0] = f2bf(WQ0[sl].x); bq[1] = f2bf(WQ0[sl].y);
            bq[2] = f2bf(WQ0[sl].z); bq[3] = f2bf(WQ0[sl].w);
            bq[4] = f2bf(WQ1[sl].x); bq[5] = f2bf(WQ1[sl].y);
            bq[6] = f2bf(WQ1[sl].z); bq[7] = f2bf(WQ1[sl].w);
            bk[0] = f2bf(WK0[sl].x); bk[1] = f2bf(WK0[sl].y);
            bk[2] = f2bf(WK0[sl].z); bk[3] = f2bf(WK0[sl].w);
            bk[4] = f2bf(WK1[sl].x); bk[5] = f2bf(WK1[sl].y);
            bk[6] = f2bf(WK1[sl].z); bk[7] = f2bf(WK1[sl].w);

            __builtin_amdgcn_wave_barrier();   // staging done before A reads

            // issue lookahead chunk into the now-free slot
            if (c + 3 < 16) LD_CHUNK(c + 3, sl);

            // A-frag: S[sa][d] = h[d][sa], d = chunk-local kb*8+i
            bf16x8 af;
            #pragma unroll
            for (int i = 0; i < 8; ++i)
                af[i] = f2bf(st[wv][kb * 8 + i][sa]);

            accQ = __builtin_amdgcn_mfma_f32_16x16x32_bf16(af, bq, accQ, 0, 0, 0);
            accK = __builtin_amdgcn_mfma_f32_16x16x32_bf16(af, bk, accK, 0, 0, 0);
            __builtin_amdgcn_wave_barrier();   // tile reads done before re-stage
        }
#undef LD_CHUNK

        // D mapping (verified): col = lane&15 (=a), row = (lane>>4)*4+reg (=s)
        #pragma unroll
        for (int r = 0; r < 4; ++r) {
            qp[wv][kb * 4 + r][sa] = accQ[r];
            kp[wv][kb * 4 + r][sa] = accK[r];
        }
    }
    __syncthreads();

    // ---------------- reduce the 8 wave partials --------------------------
    {
        const int idx = tid & 255;
        const int s2 = idx >> 4, a2 = idx & 15;
        if (tid < 256) {
            float q = 0.f;
            #pragma unroll
            for (int w = 0; w < NW; ++w) q += qp[w][s2][a2];
            Qs[s2][a2] = q;
        } else {
            float k = 0.f;
            #pragma unroll
            for (int w = 0; w < NW; ++w) k += kp[w][s2][a2];
            Ks[s2][a2] = k;
        }
    }
    __syncthreads();

    // ---------------- Phase 2: scores + softmax + fold gate ---------------
    const float g = gate[0];
    if (tid < 256) {
        const int ss = tid >> 4;   // query slot
        const int tt = tid & 15;   // key slot
        float sc = 0.f;
        #pragma unroll
        for (int a4 = 0; a4 < 16; a4 += 4) {
            float4 qv = *(const float4*)&Qs[ss][a4];
            float4 kv = *(const float4*)&Ks[tt][a4];
            sc = fmaf(qv.x, kv.x, sc);
            sc = fmaf(qv.y, kv.y, sc);
            sc = fmaf(qv.z, kv.z, sc);
            sc = fmaf(qv.w, kv.w, sc);
        }
        sc *= 0.25f;  // D_ATTN^-0.5

        float m = sc;
        #pragma unroll
        for (int o = 8; o > 0; o >>= 1) m = fmaxf(m, __shfl_xor(m, o, 16));
        float e = __expf(sc - m);
        float sm = e;
        #pragma unroll
        for (int o = 8; o > 0; o >>= 1) sm += __shfl_xor(sm, o, 16);
        Ms[ss][tt] = g * (e / sm);
    }
    __syncthreads();

    // ---------------- Phase 3: operand-swapped PV, zero global reads ------
    // D'[m=s][n=d-row] = sum_t Ms[s][t] * h[d_base+n][t]:
    //   A-frag (hoisted): lane holds Ms[sa][kb*8+i]  (kb>=2 -> t>=16 -> 0)
    //   B-frag (per tile): lane reads st[sa][kb*8 .. +7] (h row sa, cols t)
    //   D' lands: lane (sa,kb) = PV for out[d_base+sa][kb*4 .. +3]
    {
        float (* __restrict__ stw)[20] = st[wv];

        bf16x8 afrag = {0, 0, 0, 0, 0, 0, 0, 0};
        if (kb < 2) {
            const float* mp = &Ms[sa][kb * 8];
            float4 m0 = *(const float4*)mp;
            float4 m1 = *(const float4*)(mp + 4);
            afrag[0] = f2bf(m0.x); afrag[1] = f2bf(m0.y);
            afrag[2] = f2bf(m0.z); afrag[3] = f2bf(m0.w);
            afrag[4] = f2bf(m1.x); afrag[5] = f2bf(m1.y);
            afrag[6] = f2bf(m1.z); afrag[7] = f2bf(m1.w);
        }

        #pragma unroll
        for (int it = 0; it < 32; ++it) {
            // stage tile from registers (rows 0..15)
            *(float4*)&stw[row][quad * 4] = H[it];
            __builtin_amdgcn_wave_barrier();

            // B-frag: h[d_base+sa][t], t = kb*8..+7 (kb>=2 lanes -> zeros)
            const float* bp = &stw[sa][(kb & 1) * 8];
            float4 bb0 = *(const float4*)bp;
            float4 bb1 = *(const float4*)(bp + 4);
            if (kb >= 2) {
                bb0 = make_float4(0.f, 0.f, 0.f, 0.f);
                bb1 = make_float4(0.f, 0.f, 0.f, 0.f);
            }
            // residual: h[d_base+sa][kb*4 .. +3]
            float4 hres = *(const float4*)&stw[sa][kb * 4];

            bf16x8 bfr;
            bfr[0] = f2bf(bb0.x); bfr[1] = f2bf(bb0.y);
            bfr[2] = f2bf(bb0.z); bfr[3] = f2bf(bb0.w);
            bfr[4] = f2bf(bb1.x); bfr[5] = f2bf(bb1.y);
            bfr[6] = f2bf(bb1.z); bfr[7] = f2bf(bb1.w);

            f32x4 acc = {0.f, 0.f, 0.f, 0.f};
            acc = __builtin_amdgcn_mfma_f32_16x16x32_bf16(afrag, bfr, acc, 0, 0, 0);

            f32x4 o;
            o[0] = hres.x + acc[0];
            o[1] = hres.y + acc[1];
            o[2] = hres.z + acc[2];
            o[3] = hres.w + acc[3];
            const size_t orow = (size_t)(d0w + it * 16 + sa) * DS + kb * 4;
            __builtin_nontemporal_store(o, (f32x4*)(obase + orow));
            __builtin_amdgcn_wave_barrier();   // reads done before next stage
        }
    }
}

extern "C" void kernel_launch(void* const* d_in, const int* in_sizes, int n_in,
                              void* d_out, int out_size, void* d_ws, size_t ws_size,
                              hipStream_t stream) {
    const float* h    = (const float*)d_in[0];
    const float* Wq   = (const float*)d_in[1];
    const float* Wk   = (const float*)d_in[2];
    const float* gate = (const float*)d_in[3];
    float* out = (float*)d_out;
    (void)in_sizes; (void)n_in; (void)out_size; (void)d_ws; (void)ws_size;

    ica_fused<<<1024, 512, 0, stream>>>(h, Wq, Wk, gate, out);
}

// Round 13
// 116.672 us; speedup vs baseline: 2.1493x; 2.1493x over previous
//
#include <hip/hip_runtime.h>
#include <hip/hip_bf16.h>

// IntraCellularAttention: B=1024, D_INNER=4096, D_STATE=16, D_ATTN=16
// out[b,d,s] = h[b,d,s] + gate * sum_t attn[b,s,t] * h[b,d,t]
// attn[s,t] = softmax_t( (Q K^T)[s,t] * 0.25 ),  Q[s,a] = sum_d h[b,d,s] Wq[a,d]
//
// Register-resident h: 512 threads (8 waves), 1 block/batch, grid 1024.
// Each lane holds 32 float4 of h loaded ONCE, fully coalesced, 3-chunk
// lookahead. launch_bounds(512,1).
// ROUND-12 LESSON (do not undo): H[] stays in registers ONLY because each
// H[it] has an arithmetic use in phase 3 (residual add). Making H's last
// use a ds_write (round 12) caused the allocator to spill all 128 regs to
// scratch (VGPR 48, +370MB HBM traffic, 2.2x slower).
//   Phase 1: per 32-row chunk: regs -> LDS tile -> col-read A-frag,
//            mfma_16x16x32_bf16 vs W row slices (L2).
//   Phase 2: softmax on 256 threads, fold gate into Ms.
//   Phase 3: TWO 16-row tiles per iteration through the 32-row LDS tile
//            (half the barriers of round 11), MFMA with hoisted Ms B-frag,
//            transpose-back via LDS, residual from H registers, NT f4 stores.

constexpr int DI = 4096;
constexpr int DS = 16;
constexpr int NW = 8;                       // waves per block

typedef __attribute__((ext_vector_type(8))) short bf16x8;
typedef __attribute__((ext_vector_type(4))) float f32x4;

static __device__ __forceinline__ short f2bf(float x) {
    union { __hip_bfloat16 h; short s; } u;
    u.h = __float2bfloat16(x);
    return u.s;
}

__global__ __launch_bounds__(512, 1) void ica_fused(
    const float* __restrict__ h,
    const float* __restrict__ Wq,
    const float* __restrict__ Wk,
    const float* __restrict__ gate,
    float* __restrict__ out)
{
    const int b    = blockIdx.x;
    const int tid  = threadIdx.x;
    const int lane = tid & 63;
    const int wv   = tid >> 6;              // 0..7

    const float* __restrict__ hbase = h   + (size_t)b * (DI * DS);
    float*       __restrict__ obase = out + (size_t)b * (DI * DS);

    __shared__ float st[NW][32][20];        // per-wave transpose tile
    __shared__ float qp[NW][16][20];        // Q partials [w][s][a]
    __shared__ float kp[NW][16][20];        // K partials
    __shared__ float Qs[16][20];
    __shared__ float Ks[16][20];
    __shared__ float Ms[16][20];            // Ms[s][t] = g * attn[s][t]

    const int sa   = lane & 15;             // A/B row index and MFMA col
    const int kb   = lane >> 4;             // k-subblock 0..3
    const int row  = lane >> 2;             // coalesced-layout row (0..15)
    const int quad = lane & 3;              // float4 slot within row

    // wave's 512 rows as 2048 float4; lane's j-th f4 = row j*16+row, quad
    const float4* __restrict__ h4 = (const float4*)hbase + (size_t)wv * 2048;
    const int d0w = wv * 512;

    float4 H[32];                           // register-resident h slice

    // ---------------- Phase 1: Q,K via MFMA, regs->LDS transpose ----------
    {
        const float* __restrict__ wqb = Wq + (size_t)sa * DI;
        const float* __restrict__ wkb = Wk + (size_t)sa * DI;

        f32x4 accQ = {0.f, 0.f, 0.f, 0.f};
        f32x4 accK = {0.f, 0.f, 0.f, 0.f};

        float4 WQ0[3], WQ1[3], WK0[3], WK1[3];   // 3-slot W landing (L2)

#define LD_CHUNK(C, SL) do {                                                \
        H[2*(C)]   = h4[(2*(C)) * 64 + lane];                               \
        H[2*(C)+1] = h4[(2*(C)+1) * 64 + lane];                             \
        const int db_ = d0w + (C) * 32 + kb * 8;                            \
        WQ0[SL] = *(const float4*)(wqb + db_);                              \
        WQ1[SL] = *(const float4*)(wqb + db_ + 4);                          \
        WK0[SL] = *(const float4*)(wkb + db_);                              \
        WK1[SL] = *(const float4*)(wkb + db_ + 4);                          \
    } while (0)

        LD_CHUNK(0, 0);
        LD_CHUNK(1, 1);
        LD_CHUNK(2, 2);

        #pragma unroll
        for (int c = 0; c < 16; ++c) {
            const int sl = c % 3;
            // stage chunk c (32 rows) into the wave tile
            *(float4*)&st[wv][row][quad * 4]      = H[2*c];
            *(float4*)&st[wv][row + 16][quad * 4] = H[2*c + 1];

            // consume this slot's W into bf16 regs BEFORE the lookahead
            // overwrites it (lookahead distance == slot count)
            bf16x8 bq, bk;
            bq[0] = f2bf(WQ0[sl].x); bq[1] = f2bf(WQ0[sl].y);
            bq[2] = f2bf(WQ0[sl].z); bq[3] = f2bf(WQ0[sl].w);
            bq[4] = f2bf(WQ1[sl].x); bq[5] = f2bf(WQ1[sl].y);
            bq[6] = f2bf(WQ1[sl].z); bq[7] = f2bf(WQ1[sl].w);
            bk[0] = f2bf(WK0[sl].x); bk[1] = f2bf(WK0[sl].y);
            bk[2] = f2bf(WK0[sl].z); bk[3] = f2bf(WK0[sl].w);
            bk[4] = f2bf(WK1[sl].x); bk[5] = f2bf(WK1[sl].y);
            bk[6] = f2bf(WK1[sl].z); bk[7] = f2bf(WK1[sl].w);

            __builtin_amdgcn_wave_barrier();   // staging done before A reads

            // issue lookahead chunk into the now-free slot
            if (c + 3 < 16) LD_CHUNK(c + 3, sl);

            // A-frag: S[sa][d] = h[d][sa], d = chunk-local kb*8+i
            bf16x8 af;
            #pragma unroll
            for (int i = 0; i < 8; ++i)
                af[i] = f2bf(st[wv][kb * 8 + i][sa]);

            accQ = __builtin_amdgcn_mfma_f32_16x16x32_bf16(af, bq, accQ, 0, 0, 0);
            accK = __builtin_amdgcn_mfma_f32_16x16x32_bf16(af, bk, accK, 0, 0, 0);
            __builtin_amdgcn_wave_barrier();   // tile reads done before re-stage
        }
#undef LD_CHUNK

        // D mapping (verified): col = lane&15 (=a), row = (lane>>4)*4+reg (=s)
        #pragma unroll
        for (int r = 0; r < 4; ++r) {
            qp[wv][kb * 4 + r][sa] = accQ[r];
            kp[wv][kb * 4 + r][sa] = accK[r];
        }
    }
    __syncthreads();

    // ---------------- reduce the 8 wave partials --------------------------
    {
        const int idx = tid & 255;
        const int s2 = idx >> 4, a2 = idx & 15;
        if (tid < 256) {
            float q = 0.f;
            #pragma unroll
            for (int w = 0; w < NW; ++w) q += qp[w][s2][a2];
            Qs[s2][a2] = q;
        } else {
            float k = 0.f;
            #pragma unroll
            for (int w = 0; w < NW; ++w) k += kp[w][s2][a2];
            Ks[s2][a2] = k;
        }
    }
    __syncthreads();

    // ---------------- Phase 2: scores + softmax + fold gate ---------------
    const float g = gate[0];
    if (tid < 256) {
        const int ss = tid >> 4;   // query slot
        const int tt = tid & 15;   // key slot
        float sc = 0.f;
        #pragma unroll
        for (int a4 = 0; a4 < 16; a4 += 4) {
            float4 qv = *(const float4*)&Qs[ss][a4];
            float4 kv = *(const float4*)&Ks[tt][a4];
            sc = fmaf(qv.x, kv.x, sc);
            sc = fmaf(qv.y, kv.y, sc);
            sc = fmaf(qv.z, kv.z, sc);
            sc = fmaf(qv.w, kv.w, sc);
        }
        sc *= 0.25f;  // D_ATTN^-0.5

        float m = sc;
        #pragma unroll
        for (int o = 8; o > 0; o >>= 1) m = fmaxf(m, __shfl_xor(m, o, 16));
        float e = __expf(sc - m);
        float sm = e;
        #pragma unroll
        for (int o = 8; o > 0; o >>= 1) sm += __shfl_xor(sm, o, 16);
        Ms[ss][tt] = g * (e / sm);
    }
    __syncthreads();

    // ---------------- Phase 3: PV, two tiles per barrier window -----------
    {
        float (* __restrict__ stw)[20] = st[wv];

        // hoisted B fragment: B[k=t][col=s] = Ms[s][t], zero for t>=16
        bf16x8 bfrag = {0, 0, 0, 0, 0, 0, 0, 0};
        if (kb < 2) {
            const float* mp = &Ms[sa][kb * 8];
            float4 m0 = *(const float4*)mp;
            float4 m1 = *(const float4*)(mp + 4);
            bfrag[0] = f2bf(m0.x); bfrag[1] = f2bf(m0.y);
            bfrag[2] = f2bf(m0.z); bfrag[3] = f2bf(m0.w);
            bfrag[4] = f2bf(m1.x); bfrag[5] = f2bf(m1.y);
            bfrag[6] = f2bf(m1.z); bfrag[7] = f2bf(m1.w);
        }

        #pragma unroll
        for (int it = 0; it < 16; ++it) {
            // stage two tiles from registers (rows 0..15 and 16..31)
            *(float4*)&stw[row][quad * 4]      = H[2*it];
            *(float4*)&stw[row + 16][quad * 4] = H[2*it + 1];
            __builtin_amdgcn_wave_barrier();

            // A-frags: tileX[sa][(kb&1)*8 ..+7]; kb>=2 lanes carry K-pad 0
            const float* apA = &stw[sa][(kb & 1) * 8];
            const float* apB = &stw[16 + sa][(kb & 1) * 8];
            float4 aA0 = *(const float4*)apA;
            float4 aA1 = *(const float4*)(apA + 4);
            float4 aB0 = *(const float4*)apB;
            float4 aB1 = *(const float4*)(apB + 4);
            if (kb >= 2) {
                aA0 = make_float4(0.f, 0.f, 0.f, 0.f);
                aA1 = make_float4(0.f, 0.f, 0.f, 0.f);
                aB0 = make_float4(0.f, 0.f, 0.f, 0.f);
                aB1 = make_float4(0.f, 0.f, 0.f, 0.f);
            }
            bf16x8 afA, afB;
            afA[0] = f2bf(aA0.x); afA[1] = f2bf(aA0.y);
            afA[2] = f2bf(aA0.z); afA[3] = f2bf(aA0.w);
            afA[4] = f2bf(aA1.x); afA[5] = f2bf(aA1.y);
            afA[6] = f2bf(aA1.z); afA[7] = f2bf(aA1.w);
            afB[0] = f2bf(aB0.x); afB[1] = f2bf(aB0.y);
            afB[2] = f2bf(aB0.z); afB[3] = f2bf(aB0.w);
            afB[4] = f2bf(aB1.x); afB[5] = f2bf(aB1.y);
            afB[6] = f2bf(aB1.z); afB[7] = f2bf(aB1.w);

            f32x4 accA = {0.f, 0.f, 0.f, 0.f};
            f32x4 accB = {0.f, 0.f, 0.f, 0.f};
            accA = __builtin_amdgcn_mfma_f32_16x16x32_bf16(afA, bfrag, accA, 0, 0, 0);
            accB = __builtin_amdgcn_mfma_f32_16x16x32_bf16(afB, bfrag, accB, 0, 0, 0);
            __builtin_amdgcn_wave_barrier();   // A reads done before transpose

            // transpose D (col sa, rows kb*4+r) back through the tiles
            #pragma unroll
            for (int r = 0; r < 4; ++r) {
                stw[kb * 4 + r][sa]      = accA[r];
                stw[16 + kb * 4 + r][sa] = accB[r];
            }
            __builtin_amdgcn_wave_barrier();

            float4 pvA = *(const float4*)&stw[row][quad * 4];
            float4 pvB = *(const float4*)&stw[row + 16][quad * 4];
            f32x4 oA, oB;
            oA[0] = H[2*it].x + pvA.x;
            oA[1] = H[2*it].y + pvA.y;
            oA[2] = H[2*it].z + pvA.z;
            oA[3] = H[2*it].w + pvA.w;
            oB[0] = H[2*it+1].x + pvB.x;
            oB[1] = H[2*it+1].y + pvB.y;
            oB[2] = H[2*it+1].z + pvB.z;
            oB[3] = H[2*it+1].w + pvB.w;
            const size_t orowA = (size_t)(d0w + (2*it)     * 16 + row) * DS + quad * 4;
            const size_t orowB = (size_t)(d0w + (2*it + 1) * 16 + row) * DS + quad * 4;
            __builtin_nontemporal_store(oA, (f32x4*)(obase + orowA));
            __builtin_nontemporal_store(oB, (f32x4*)(obase + orowB));
            __builtin_amdgcn_wave_barrier();   // pv reads done before next stage
        }
    }
}

extern "C" void kernel_launch(void* const* d_in, const int* in_sizes, int n_in,
                              void* d_out, int out_size, void* d_ws, size_t ws_size,
                              hipStream_t stream) {
    const float* h    = (const float*)d_in[0];
    const float* Wq   = (const float*)d_in[1];
    const float* Wk   = (const float*)d_in[2];
    const float* gate = (const float*)d_in[3];
    float* out = (float*)d_out;
    (void)in_sizes; (void)n_in; (void)out_size; (void)d_ws; (void)ws_size;

    ica_fused<<<1024, 512, 0, stream>>>(h, Wq, Wk, gate, out);
}